// Round 8
// baseline (37.999 us; speedup 1.0000x reference)
//
#include <hip/hip_runtime.h>

// YOLO loss on (B,7,7,30) fp32 pred/target -> scalar.
// R8 = R7 (4 lanes/cell, single-pass coalesced, shuffle gather) + 2-chunk
// unroll for deeper MLP (8 dwordx4 loads in flight/lane) + hoisted bounds
// guard (only the final chunk runs the clamp; full chunks are unguarded).
// Context: R2/R4/R7 all plateau at 36-38us (~5.5 TB/s effective, replays
// L3-resident yet not faster than cold) -> suspected memory-system service
// ceiling; this probes whether the last 10-15% is latency/ILP instead.

#define NC 30

typedef float f4 __attribute__((ext_vector_type(4), aligned(4)));

__device__ __forceinline__ float sq(float x) { return x * x; }

__device__ __forceinline__ void make_box(float cx, float cy, float w, float h,
                                         float jf, float kf, float b[4]) {
    float x = (cx + jf) * (1.0f / 7.0f);
    float y = (cy + kf) * (1.0f / 7.0f);
    b[0] = x - w * 0.5f;
    b[1] = y - h * 0.5f;
    b[2] = x + w * 0.5f;
    b[3] = y + h * 0.5f;
}

__device__ __forceinline__ float iou(const float a[4], const float b[4]) {
    float ix1 = fmaxf(a[0], b[0]);
    float iy1 = fmaxf(a[1], b[1]);
    float ix2 = fminf(a[2], b[2]);
    float iy2 = fminf(a[3], b[3]);
    float iw = fmaxf(ix2 - ix1, 0.0f);
    float ih = fmaxf(iy2 - iy1, 0.0f);
    float inter = iw * ih;
    float area_a = (a[2] - a[0]) * (a[3] - a[1]);
    float area_b = (b[2] - b[0]) * (b[3] - b[1]);
    return inter > 0.0f ? inter / (area_a + area_b - inter) : 0.0f;
}

struct CellRegs {
    f4 Pa, Pb, Ta, Tb;
};

__device__ __forceinline__ void load_chunk(const float* __restrict__ pred,
                                           const float* __restrict__ targ,
                                           int chunk, int t, int total_dw,
                                           bool guard, CellRegs& r) {
    int cell = chunk * 64 + (t >> 2);
    int q = t & 3;
    int dwbase = cell * NC + 8 * q;
    int ldbase = dwbase;
    int shift = 0;
    if (guard) {  // uniform branch: only the final chunk takes it
        if (dwbase + 8 > total_dw) {
            ldbase = total_dw - 8;
            shift = dwbase - ldbase;  // == 2 for the single overshooting lane
        }
    }
    r.Pa = *reinterpret_cast<const f4*>(pred + ldbase);
    r.Pb = *reinterpret_cast<const f4*>(pred + ldbase + 4);
    r.Ta = *reinterpret_cast<const f4*>(targ + ldbase);
    r.Tb = *reinterpret_cast<const f4*>(targ + ldbase + 4);
    if (guard && shift) {  // remap loaded -> nominal channel positions
        f4 p0 = r.Pa, p1 = r.Pb, u0 = r.Ta, u1 = r.Tb;
        r.Pa[0] = p0[2]; r.Pa[1] = p0[3]; r.Pa[2] = p1[0]; r.Pa[3] = p1[1];
        r.Pb[0] = p1[2]; r.Pb[1] = p1[3]; r.Pb[2] = 0.f;   r.Pb[3] = 0.f;
        r.Ta[0] = u0[2]; r.Ta[1] = u0[3]; r.Ta[2] = u1[0]; r.Ta[3] = u1[1];
        r.Tb[0] = u1[2]; r.Tb[1] = u1[3]; r.Tb[2] = 0.f;   r.Tb[3] = 0.f;
    }
}

__device__ __forceinline__ float compute_chunk(const CellRegs& r, int chunk,
                                               int t) {
    int q = t & 3;
    int gbase = t & ~3;
    int cell = chunk * 64 + (t >> 2);

    // obj mask: T4 lives in group-leader's Tb[0]
    float t4 = __shfl(r.Tb[0], gbase, 64);
    float objw = t4 > 0.0f ? 1.0f : 0.0f;

    // cls fully in-lane: ch = 8q+e (Pa: e<4) / 8q+4+e (Pb)
    float cls = 0.0f;
#pragma unroll
    for (int e = 0; e < 4; ++e) {
        int ch = 8 * q + e;
        float d = r.Pa[e] - r.Ta[e];
        cls += (ch >= 10 && ch < NC) ? d * d : 0.0f;
    }
#pragma unroll
    for (int e = 0; e < 4; ++e) {
        int ch = 8 * q + 4 + e;
        float d = r.Pb[e] - r.Tb[e];
        cls += (ch >= 10 && ch < NC) ? d * d : 0.0f;
    }
    float res = objw * cls;

    // gather for coord: lane q=1 holds d8..11
    float P8 = __shfl(r.Pa[0], gbase + 1, 64);
    float P9 = __shfl(r.Pa[1], gbase + 1, 64);
    float T8 = __shfl(r.Ta[0], gbase + 1, 64);  // T9 unused by reference

    if (q == 0) {
        int q7 = cell / 7;
        float kf = (float)(cell - q7 * 7);
        float jf = (float)(q7 % 7);

        float b1[4], b2[4], tbx[4];
        make_box(r.Pa[0], r.Pa[1], r.Pa[2], r.Pa[3], jf, kf, b1);
        make_box(r.Pb[1], r.Pb[2], r.Pb[3], P8, jf, kf, b2);
        make_box(r.Ta[0], r.Ta[1], r.Ta[2], r.Ta[3], jf, kf, tbx);

        float i1 = iou(b1, tbx);
        float i2 = iou(b2, tbx);

        bool obj = r.Tb[0] > 0.0f;
        bool pick1 = i1 >= i2;

        float coo1 = 5.0f * (sq(r.Pa[0] - r.Ta[0]) + sq(r.Pa[1] - r.Ta[1]) +
                             sq(sqrtf(r.Pa[2]) - sqrtf(r.Ta[2])) +
                             sq(sqrtf(r.Pa[3]) - sqrtf(r.Ta[3]))) +
                     sq(r.Pb[0] - i1);
        float non1 = 0.5f * sq(r.Pb[0] - i2);

        float coo2 = 5.0f * (sq(r.Pb[1] - r.Tb[1]) + sq(r.Pb[2] - r.Tb[2]) +
                             sq(sqrtf(r.Pb[3]) - sqrtf(r.Tb[3])) +
                             sq(sqrtf(P8) - sqrtf(T8))) +
                     sq(P9 - i2);
        float non2 = 0.5f * sq(P9 - i1);

        float noobj = 0.5f * (r.Pb[0] * r.Pb[0] + P9 * P9);

        float resp = pick1 ? (coo1 + non1) : (coo2 + non2);
        res += obj ? resp : noobj;
    }
    return res;
}

template <bool USE_WS>
__global__ __launch_bounds__(256) void yolo_partial_kernel(
    const float* __restrict__ pred, const float* __restrict__ targ,
    float* __restrict__ dst, int ncells, float scale) {
    int t = threadIdx.x;
    int nfull = ncells / 64;      // full 64-cell chunks
    int lastc = nfull - 1;
    int total_dw = ncells * NC;
    int G = gridDim.x;

    float acc = 0.0f;

    // paired chunks for deeper MLP: 8 dwordx4 loads in flight per lane
    int c = blockIdx.x;
    for (; c + G < nfull; c += 2 * G) {
        int c1 = c + G;
        CellRegs r0, r1;
        load_chunk(pred, targ, c, t, total_dw, false, r0);
        load_chunk(pred, targ, c1, t, total_dw, c1 == lastc, r1);
        acc += compute_chunk(r0, c, t);
        acc += compute_chunk(r1, c1, t);
    }
    if (c < nfull) {  // leftover single chunk
        CellRegs r0;
        load_chunk(pred, targ, c, t, total_dw, c == lastc, r0);
        acc += compute_chunk(r0, c, t);
    }

    // tail cells (ncells % 64 != 0) — scalar path on block 0 (not hit here)
    int rem = ncells - nfull * 64;
    if (rem > 0 && blockIdx.x == 0 && t < rem) {
        int cell = nfull * 64 + t;
        const float* pp = pred + (size_t)cell * NC;
        const float* tt = targ + (size_t)cell * NC;
        float P[NC], T[NC];
#pragma unroll
        for (int e = 0; e < NC; ++e) {
            P[e] = pp[e];
            T[e] = tt[e];
        }
        int q7 = cell / 7;
        float kf = (float)(cell - q7 * 7);
        float jf = (float)(q7 % 7);
        float b1[4], b2[4], tbx[4];
        make_box(P[0], P[1], P[2], P[3], jf, kf, b1);
        make_box(P[5], P[6], P[7], P[8], jf, kf, b2);
        make_box(T[0], T[1], T[2], T[3], jf, kf, tbx);
        float i1 = iou(b1, tbx);
        float i2 = iou(b2, tbx);
        bool obj = T[4] > 0.0f;
        bool pick1 = i1 >= i2;
        float cls = 0.0f;
#pragma unroll
        for (int e = 10; e < NC; ++e) {
            float d = P[e] - T[e];
            cls += d * d;
        }
        float coo1 = 5.0f * (sq(P[0] - T[0]) + sq(P[1] - T[1]) +
                             sq(sqrtf(P[2]) - sqrtf(T[2])) +
                             sq(sqrtf(P[3]) - sqrtf(T[3]))) +
                     sq(P[4] - i1);
        float non1 = 0.5f * sq(P[4] - i2);
        float coo2 = 5.0f * (sq(P[5] - T[5]) + sq(P[6] - T[6]) +
                             sq(sqrtf(P[7]) - sqrtf(T[7])) +
                             sq(sqrtf(P[8]) - sqrtf(T[8]))) +
                     sq(P[9] - i2);
        float non2 = 0.5f * sq(P[9] - i1);
        float noobj = 0.5f * (P[4] * P[4] + P[9] * P[9]);
        float resp = pick1 ? (coo1 + non1) : (coo2 + non2);
        acc += obj ? (resp + cls) : noobj;
    }

    // block reduction, one plain store per block
#pragma unroll
    for (int off = 32; off > 0; off >>= 1) acc += __shfl_down(acc, off);

    __shared__ float wsum[4];
    int wave = t >> 6;
    int lane = t & 63;
    if (lane == 0) wsum[wave] = acc;
    __syncthreads();

    if (t == 0) {
        float s = wsum[0] + wsum[1] + wsum[2] + wsum[3];
        if (USE_WS) {
            dst[blockIdx.x] = s * scale;
        } else {
            atomicAdd(dst, s * scale);
        }
    }
}

__global__ __launch_bounds__(1024) void reduce_kernel(
    const float* __restrict__ ws, float* __restrict__ out, int n) {
    float s = 0.0f;
    for (int i = threadIdx.x; i < n; i += 1024) s += ws[i];
#pragma unroll
    for (int off = 32; off > 0; off >>= 1) s += __shfl_down(s, off);

    __shared__ float acc[16];
    int wave = threadIdx.x >> 6;
    int lane = threadIdx.x & 63;
    if (lane == 0) acc[wave] = s;
    __syncthreads();

    if (threadIdx.x == 0) {
        float tot = 0.0f;
#pragma unroll
        for (int w = 0; w < 16; ++w) tot += acc[w];
        out[0] = tot;
    }
}

extern "C" void kernel_launch(void* const* d_in, const int* in_sizes, int n_in,
                              void* d_out, int out_size, void* d_ws, size_t ws_size,
                              hipStream_t stream) {
    const float* pred = (const float*)d_in[0];
    const float* targ = (const float*)d_in[1];
    float* out = (float*)d_out;

    int ncells = in_sizes[0] / NC;  // B*7*7
    int batch = ncells / 49;        // B
    float inv_b = 1.0f / (float)batch;

    int nfull = ncells / 64;
    int grid = nfull < 2048 ? (nfull > 0 ? nfull : 1) : 2048;

    if (ws_size >= (size_t)grid * sizeof(float)) {
        float* ws = (float*)d_ws;
        yolo_partial_kernel<true><<<grid, 256, 0, stream>>>(pred, targ, ws,
                                                            ncells, inv_b);
        reduce_kernel<<<1, 1024, 0, stream>>>(ws, out, grid);
    } else {
        hipMemsetAsync(out, 0, sizeof(float), stream);
        yolo_partial_kernel<false><<<grid, 256, 0, stream>>>(pred, targ, out,
                                                             ncells, inv_b);
    }
}